// Round 11
// baseline (2985.590 us; speedup 1.0000x reference)
//
#include <hip/hip_runtime.h>
#include <hip/hip_bf16.h>
#include <cstdint>

#define NUM_TOKENS 8192
#define IN_DIM 4096
#define OUT_DIM 4096
#define NUM_AD 8
#define RANK 64
#define RTOT (NUM_AD * RANK)           // 512
#define KAUG (IN_DIM + RTOT)           // 4608

typedef __bf16 bf16x8 __attribute__((ext_vector_type(8)));
typedef float f32x4 __attribute__((ext_vector_type(4)));
typedef unsigned short ushort_t;

__device__ __forceinline__ unsigned f2bf_u(float f) {
  unsigned u = __float_as_uint(f);
  return (u + 0x7FFFu + ((u >> 16) & 1u)) >> 16;   // round-to-nearest-even
}
__device__ __forceinline__ uint2 pack4(float4 v) {
  uint2 r;
  r.x = f2bf_u(v.x) | (f2bf_u(v.y) << 16);
  r.y = f2bf_u(v.z) | (f2bf_u(v.w) << 16);
  return r;
}
__device__ __forceinline__ uint4 pack8(float4 a, float4 b) {
  uint2 p = pack4(a), q = pack4(b);
  return make_uint4(p.x, p.y, q.x, q.y);
}

#define AS1(p) (const __attribute__((address_space(1))) void*)(p)
#define AS3(p) (__attribute__((address_space(3))) void*)(p)
#define GLD(gp, lp) __builtin_amdgcn_global_load_lds(AS1(gp), AS3(lp), 16, 0, 0)
#define LGKM(n) asm volatile("s_waitcnt lgkmcnt(" #n ")" ::: "memory")
#define VMC(n)  asm volatile("s_waitcnt vmcnt(" #n ")" ::: "memory")
#define SB()    __builtin_amdgcn_sched_barrier(0)

// ---------- One merged conversion kernel: x, wgt, A_buffer, B_buffer -> bf16 ----------
#define XT8 (NUM_TOKENS * IN_DIM / 8)         // 4194304
#define WT8 (OUT_DIM * IN_DIM / 8)            // 2097152
#define AT8 (RTOT * IN_DIM / 8)               //  262144
#define BT8 (NUM_AD * OUT_DIM * RANK / 8)     //  262144
__global__ void k_cvt_all(const float* __restrict__ x, const float* __restrict__ wgt,
                          const float* __restrict__ Abuf, const float* __restrict__ Bbuf,
                          ushort_t* __restrict__ Xaug, ushort_t* __restrict__ Waug,
                          ushort_t* __restrict__ Abf) {
  int i = blockIdx.x * blockDim.x + threadIdx.x;
  if (i < XT8 + WT8) {                 // x -> Xaug cols 0..4095 | wgt -> Waug cols 0..4095
    const float* src = (i < XT8) ? x : wgt;
    ushort_t* dst = (i < XT8) ? Xaug : Waug;
    size_t idx = ((size_t)(i < XT8 ? i : i - XT8)) << 3;
    int row = (int)(idx >> 12);
    int col = (int)(idx & 4095);
    float4 v0 = *reinterpret_cast<const float4*>(src + idx);
    float4 v1 = *reinterpret_cast<const float4*>(src + idx + 4);
    *reinterpret_cast<uint4*>(dst + (size_t)row * KAUG + col) = pack8(v0, v1);
  } else if (i < XT8 + WT8 + AT8) {    // A_buffer -> Abf flat [512][4096]
    size_t idx = ((size_t)(i - XT8 - WT8)) << 3;
    float4 v0 = *reinterpret_cast<const float4*>(Abuf + idx);
    float4 v1 = *reinterpret_cast<const float4*>(Abuf + idx + 4);
    *reinterpret_cast<uint4*>(Abf + idx) = pack8(v0, v1);
  } else {                             // B_buffer [8][4096][64] -> Waug cols 4096+a*64+r
    size_t idx = ((size_t)(i - XT8 - WT8 - AT8)) << 3;
    int a = (int)(idx >> 18);
    int rem = (int)(idx & 262143);
    int o = rem >> 6;
    int r = rem & 63;
    float4 v0 = *reinterpret_cast<const float4*>(Bbuf + idx);
    float4 v1 = *reinterpret_cast<const float4*>(Bbuf + idx + 4);
    *reinterpret_cast<uint4*>(Waug + (size_t)o * KAUG + IN_DIM + a * RANK + r) = pack8(v0, v1);
  }
}

// ---------- LoRA-A GEMM v2 (R10-proven): 128x64 tile, 4 waves, BK=64, dbuf ----------
__global__ __launch_bounds__(256)
void gemm_lora_a(const ushort_t* __restrict__ A, const ushort_t* __restrict__ B,
                 ushort_t* __restrict__ Z, const int* __restrict__ aid) {
  extern __shared__ char lds[];
  const int tid = threadIdx.x;
  const int w = tid >> 6;
  const int l = tid & 63;
  const int wr = w >> 1, wc = w & 1;      // wave grid 2Mx2N; per-wave 64x32

  const int bid = blockIdx.x;             // nwg = 512 = 8*64 (XCD swizzle exact)
  const int swz = (bid & 7) * 64 + (bid >> 3);
  const int by = swz >> 3, bx = swz & 7;
  const int brow = by << 7, bcol = bx << 6;

  const int r0 = tid >> 3;                        // 0..31
  const int kc = ((tid & 7) ^ (r0 & 7)) << 3;     // pre-swizzled source col (elems)
  const int wofs = w << 10;                       // per-wave LDS slice (R9 lesson)

  const int lr = l & 15;
  const int lxor = (l & 7) << 4;
  const int kb0 = (l >> 4) << 4;

#define STGL(k_) do {                                                                \
    int kt = (k_); if (kt >= 64) kt -= 64;                                           \
    char* ab = lds + ((kt & 1) << 14) + wofs;                                        \
    char* bb = lds + 32768 + ((kt & 1) << 13) + wofs;                                \
    const ushort_t* spa = A + (size_t)(brow + r0) * KAUG + (kt << 6) + kc;           \
    const ushort_t* spb = B + (size_t)(bcol + r0) * IN_DIM + (kt << 6) + kc;         \
    GLD(spa, ab);                                                                    \
    GLD(spa + (size_t)32 * KAUG, ab + 4096);                                         \
    GLD(spa + (size_t)64 * KAUG, ab + 8192);                                         \
    GLD(spa + (size_t)96 * KAUG, ab + 12288);                                        \
    GLD(spb, bb);                                                                    \
    GLD(spb + (size_t)32 * IN_DIM, bb + 4096);                                       \
  } while (0)

#define LAADDR(c, mb, ks)                                                            \
  (const bf16x8*)(lds + ((c) << 14)                                                  \
                  + (wr * 64 + (mb) * 16 + lr) * 128 + ((((ks) << 6) | kb0) ^ lxor))
#define LBADDR(c, nb, ks)                                                            \
  (const bf16x8*)(lds + 32768 + ((c) << 13)                                          \
                  + (wc * 32 + (nb) * 16 + lr) * 128 + ((((ks) << 6) | kb0) ^ lxor))

  f32x4 acc[4][2] = {};

  STGL(0);
  STGL(1);
  VMC(6);
  __builtin_amdgcn_s_barrier();
  SB();

  for (int k = 0; k < 64; ++k) {
    const int c = k & 1;
    bf16x8 af[4][2], bf[2][2];
#pragma unroll
    for (int mb = 0; mb < 4; ++mb)
#pragma unroll
      for (int ks = 0; ks < 2; ++ks)
        af[mb][ks] = *LAADDR(c, mb, ks);
#pragma unroll
    for (int nb = 0; nb < 2; ++nb)
#pragma unroll
      for (int ks = 0; ks < 2; ++ks)
        bf[nb][ks] = *LBADDR(c, nb, ks);
    LGKM(0); SB();
    __builtin_amdgcn_s_barrier();      // all waves' reads of buf c drained
    STGL(k + 2);                       // overwrite buf c with tile k+2
    __builtin_amdgcn_s_setprio(1);
#pragma unroll
    for (int ks = 0; ks < 2; ++ks)
#pragma unroll
      for (int mb = 0; mb < 4; ++mb)
#pragma unroll
        for (int nb = 0; nb < 2; ++nb)
          acc[mb][nb] = __builtin_amdgcn_mfma_f32_16x16x32_bf16(
              af[mb][ks], bf[nb][ks], acc[mb][nb], 0, 0, 0);
    __builtin_amdgcn_s_setprio(0);
    VMC(6);                            // own slices of tile k+1 landed
    __builtin_amdgcn_s_barrier();      // everyone's slices visible
    SB();
  }

  const int orow = brow + wr * 64 + ((l >> 4) << 2);
#pragma unroll
  for (int mb = 0; mb < 4; ++mb) {
#pragma unroll
    for (int j = 0; j < 4; ++j) {
      int t = orow + mb * 16 + j;
      int ad = aid[t];
#pragma unroll
      for (int nb = 0; nb < 2; ++nb) {
        int cc = bcol + wc * 32 + nb * 16 + lr;
        float v = ((cc >> 6) == ad) ? acc[mb][nb][j] : 0.f;
        Z[(size_t)t * KAUG + IN_DIM + cc] = (ushort_t)f2bf_u(v);
      }
    }
  }
}

// ---------- 256^2-tile BK=32 GEMM, 64KB LDS -> 2 blocks/CU (TLP play) ----------
// C[M,N] = A[M,K](lda) x B[N,K](ldb)^T + bias.  Grid/output identical to gemm8.
// Diagnosis R5-R7: 1 block/CU lockstep rendezvous caps MfmaUtil at ~57%; intra-
// block reordering (R6/R7) can't fix it. 2 independent blocks/CU overlap one
// block's barrier waits with the other's MFMA (m97-structure TLP).
// LDS 64KB: A bufs @ c*16384, B @ 32768 + c*16384; each buf = 128 ldsrows x 128B,
// ldsrow R interleaves matrix rows {R, R+128} (keeps the PROVEN 128B-row
// (row&7)<<4 XOR conflict-free swizzle; 64B rows would 4-way conflict).
// Slot s = (t&7)^((t>>3)&7): s&4 selects row half, s&3 the col octet (verified
// element-consistent with the read swizzle symbolically).
// Ledger per tile k (R10-lora-proven): 12 ds_reads -> lgkm(0)+bar -> STG(k+2,
// 4 glds, buf c) -> 32 MFMA -> vmcnt(4) drains k+1 (k+2's 4 in flight) -> bar.
__global__ __launch_bounds__(512, 4)
void gemm8b(const ushort_t* __restrict__ A, int lda,
            const ushort_t* __restrict__ B, int ldb,
            int M, int N, int K,
            float* __restrict__ out, const float* __restrict__ bias) {
  extern __shared__ char lds[];
  const int tid = threadIdx.x;
  const int l = tid & 63;
  const int w = tid >> 6;       // 0..7
  const int wr = w >> 2;        // 0..1  (M-half)
  const int wc = w & 3;         // 0..3  (64-col slice)

  const int nbx = N >> 8;
  const int nwg = nbx * (M >> 8);
  const int cpx = nwg >> 3;
  const int bid = blockIdx.x;
  const int swz = (bid & 7) * cpx + (bid >> 3);
  const int by = swz / nbx, bx = swz - by * nbx;
  const int brow = by << 8, bcol = bx << 8;

  // stage-side: thread t -> ldsrow r0+64h, slot s (hi/lo half + col octet)
  const int r0 = tid >> 3;                        // 0..63
  const int s = (tid & 7) ^ (r0 & 7);             // swizzled slot
  const int hrow = (s & 4) << 5;                  // +128 matrix rows if s&4
  const int scol = (s & 3) << 3;                  // col octet (elems)
  const int wofs = w << 10;                       // per-wave LDS slice (R9 lesson)

  // read-side
  const int lr = l & 15;
  const int lxor = (l & 7) << 4;
  const int kb0 = (l >> 4) << 4;                  // 0,16,32,48 bytes = K quarter

  const int NTT = K >> 5;        // 144 K-tiles

#define STGN(k_) do {                                                                \
    int kt = (k_); if (kt >= NTT) kt -= NTT;                                         \
    char* ab = lds + ((kt & 1) << 14) + wofs;                                        \
    char* bb = lds + 32768 + ((kt & 1) << 14) + wofs;                                \
    const ushort_t* spa = A + (size_t)(brow + r0 + hrow) * (lda) + (kt << 5) + scol; \
    const ushort_t* spb = B + (size_t)(bcol + r0 + hrow) * (ldb) + (kt << 5) + scol; \
    GLD(spa, ab);                                                                    \
    GLD(spa + (size_t)64 * (lda), ab + 8192);                                        \
    GLD(spb, bb);                                                                    \
    GLD(spb + (size_t)64 * (ldb), bb + 8192);                                        \
  } while (0)

  // A frag mi: matrix row wr*128 + mi*16 + lr -> ldsrow mi*16+lr, byte-hi wr*64
#define LA8(c, mi)                                                                   \
  (const bf16x8*)(lds + ((c) << 14) + ((mi) * 16 + lr) * 128                         \
                  + (((wr << 6) | kb0) ^ lxor))
  // B frag nj: col wc*64 + nj*16 + lr -> ldsrow (wc&1)*64 + nj*16 + lr, hi (wc>>1)*64
#define LB8(c, nj)                                                                   \
  (const bf16x8*)(lds + 32768 + ((c) << 14)                                          \
                  + (((wc & 1) << 6) + (nj) * 16 + lr) * 128                         \
                  + ((((wc >> 1) << 6) | kb0) ^ lxor))

  f32x4 acc[8][4] = {};

  STGN(0);
  STGN(1);
  VMC(4);
  __builtin_amdgcn_s_barrier();
  SB();

  for (int k = 0; k < NTT; ++k) {
    const int c = k & 1;
    bf16x8 af[8], bf[4];
#pragma unroll
    for (int mi = 0; mi < 8; ++mi) af[mi] = *LA8(c, mi);
#pragma unroll
    for (int nj = 0; nj < 4; ++nj) bf[nj] = *LB8(c, nj);
    LGKM(0); SB();
    __builtin_amdgcn_s_barrier();      // all waves' reads of buf c drained
    STGN(k + 2);                       // overwrite buf c with tile k+2
    __builtin_amdgcn_s_setprio(1);
#pragma unroll
    for (int mi = 0; mi < 8; ++mi)
#pragma unroll
      for (int nj = 0; nj < 4; ++nj)
        acc[mi][nj] = __builtin_amdgcn_mfma_f32_16x16x32_bf16(
            af[mi], bf[nj], acc[mi][nj], 0, 0, 0);
    __builtin_amdgcn_s_setprio(0);
    VMC(4);                            // tile k+1 landed (k+2's 4 in flight)
    __builtin_amdgcn_s_barrier();      // everyone's slices visible
    SB();
  }

  // epilogue: D frag layout row=(l>>4)*4+j, col=l&15 (verified R1-R10)
  const int orow = brow + (wr << 7) + ((l >> 4) << 2);
  const int ocol = bcol + (wc << 6) + lr;
  float bb4[4];
#pragma unroll
  for (int n = 0; n < 4; ++n) bb4[n] = bias[ocol + n * 16];
#pragma unroll
  for (int mi = 0; mi < 8; ++mi)
#pragma unroll
    for (int n = 0; n < 4; ++n)
#pragma unroll
      for (int j = 0; j < 4; ++j)
        out[(size_t)(orow + mi * 16 + j) * N + ocol + n * 16] = acc[mi][n][j] + bb4[n];
}

extern "C" void kernel_launch(void* const* d_in, const int* in_sizes, int n_in,
                              void* d_out, int out_size, void* d_ws, size_t ws_size,
                              hipStream_t stream) {
  const float* x    = (const float*)d_in[0];
  const float* wgt  = (const float*)d_in[1];
  const float* bias = (const float*)d_in[2];
  const float* Abuf = (const float*)d_in[3];
  const float* Bbuf = (const float*)d_in[4];
  const int*   aid  = (const int*)d_in[5];
  float* out = (float*)d_out;

  // workspace: Xaug[8192][4608] | Waug[4096][4608] | Abf[512][4096]  (bf16 as ushort)
  ushort_t* Xaug = (ushort_t*)d_ws;
  ushort_t* Waug = Xaug + (size_t)NUM_TOKENS * KAUG;
  ushort_t* Abf  = Waug + (size_t)OUT_DIM * KAUG;

  // all conversions in one streaming launch
  k_cvt_all<<<(XT8 + WT8 + AT8 + BT8) / 256, 256, 0, stream>>>(
      x, wgt, Abuf, Bbuf, Xaug, Waug, Abf);

  // Z = mask(X @ A_flat^T) into Xaug cols 4096..4607: M=8192 N=512 K=4096
  gemm_lora_a<<<512, 256, 49152, stream>>>(Xaug, Abf, Xaug, aid);

  // out = Xaug @ Waug^T + bias: M=8192 N=4096 K=4608 (144 K-tiles of 32)
  gemm8b<<<(NUM_TOKENS / 256) * (OUT_DIM / 256), 512, 65536, stream>>>(
      Xaug, KAUG, Waug, KAUG, NUM_TOKENS, OUT_DIM, KAUG, out, bias);
}

// Round 12
// 334.026 us; speedup vs baseline: 8.9382x; 8.9382x over previous
//
#include <hip/hip_runtime.h>
#include <hip/hip_bf16.h>
#include <cstdint>

#define NUM_TOKENS 8192
#define IN_DIM 4096
#define OUT_DIM 4096
#define NUM_AD 8
#define RANK 64
#define RTOT (NUM_AD * RANK)           // 512
#define KAUG (IN_DIM + RTOT)           // 4608

typedef __bf16 bf16x8 __attribute__((ext_vector_type(8)));
typedef float f32x4 __attribute__((ext_vector_type(4)));
typedef unsigned short ushort_t;

__device__ __forceinline__ unsigned f2bf_u(float f) {
  unsigned u = __float_as_uint(f);
  return (u + 0x7FFFu + ((u >> 16) & 1u)) >> 16;   // round-to-nearest-even
}
__device__ __forceinline__ uint2 pack4(float4 v) {
  uint2 r;
  r.x = f2bf_u(v.x) | (f2bf_u(v.y) << 16);
  r.y = f2bf_u(v.z) | (f2bf_u(v.w) << 16);
  return r;
}
__device__ __forceinline__ uint4 pack8(float4 a, float4 b) {
  uint2 p = pack4(a), q = pack4(b);
  return make_uint4(p.x, p.y, q.x, q.y);
}

#define AS1(p) (const __attribute__((address_space(1))) void*)(p)
#define AS3(p) (__attribute__((address_space(3))) void*)(p)
#define GLD(gp, lp) __builtin_amdgcn_global_load_lds(AS1(gp), AS3(lp), 16, 0, 0)
#define LGKM(n) asm volatile("s_waitcnt lgkmcnt(" #n ")" ::: "memory")
#define VMC(n)  asm volatile("s_waitcnt vmcnt(" #n ")" ::: "memory")
#define SB()    __builtin_amdgcn_sched_barrier(0)

// ---------- One merged conversion kernel: x, wgt, A_buffer, B_buffer -> bf16 ----------
#define XT8 (NUM_TOKENS * IN_DIM / 8)         // 4194304
#define WT8 (OUT_DIM * IN_DIM / 8)            // 2097152
#define AT8 (RTOT * IN_DIM / 8)               //  262144
#define BT8 (NUM_AD * OUT_DIM * RANK / 8)     //  262144
__global__ void k_cvt_all(const float* __restrict__ x, const float* __restrict__ wgt,
                          const float* __restrict__ Abuf, const float* __restrict__ Bbuf,
                          ushort_t* __restrict__ Xaug, ushort_t* __restrict__ Waug,
                          ushort_t* __restrict__ Abf) {
  int i = blockIdx.x * blockDim.x + threadIdx.x;
  if (i < XT8 + WT8) {                 // x -> Xaug cols 0..4095 | wgt -> Waug cols 0..4095
    const float* src = (i < XT8) ? x : wgt;
    ushort_t* dst = (i < XT8) ? Xaug : Waug;
    size_t idx = ((size_t)(i < XT8 ? i : i - XT8)) << 3;
    int row = (int)(idx >> 12);
    int col = (int)(idx & 4095);
    float4 v0 = *reinterpret_cast<const float4*>(src + idx);
    float4 v1 = *reinterpret_cast<const float4*>(src + idx + 4);
    *reinterpret_cast<uint4*>(dst + (size_t)row * KAUG + col) = pack8(v0, v1);
  } else if (i < XT8 + WT8 + AT8) {    // A_buffer -> Abf flat [512][4096]
    size_t idx = ((size_t)(i - XT8 - WT8)) << 3;
    float4 v0 = *reinterpret_cast<const float4*>(Abuf + idx);
    float4 v1 = *reinterpret_cast<const float4*>(Abuf + idx + 4);
    *reinterpret_cast<uint4*>(Abf + idx) = pack8(v0, v1);
  } else {                             // B_buffer [8][4096][64] -> Waug cols 4096+a*64+r
    size_t idx = ((size_t)(i - XT8 - WT8 - AT8)) << 3;
    int a = (int)(idx >> 18);
    int rem = (int)(idx & 262143);
    int o = rem >> 6;
    int r = rem & 63;
    float4 v0 = *reinterpret_cast<const float4*>(Bbuf + idx);
    float4 v1 = *reinterpret_cast<const float4*>(Bbuf + idx + 4);
    *reinterpret_cast<uint4*>(Waug + (size_t)o * KAUG + IN_DIM + a * RANK + r) = pack8(v0, v1);
  }
}

// ---------- LoRA-A GEMM v2 (R10-proven): 128x64 tile, 4 waves, BK=64, dbuf ----------
// C[8192,512] = Xaug[:, 0:4096 (ld KAUG)] @ Abf[512,4096]^T; masked bf16 -> Z cols.
// global_load_lds dest is WAVE-uniform base + lane*16 (m104): per-wave w<<10
// offset is mandatory (the R9 bug). Ledger: 2 raw barriers + vmcnt(6)/tile.
__global__ __launch_bounds__(256)
void gemm_lora_a(const ushort_t* __restrict__ A, const ushort_t* __restrict__ B,
                 ushort_t* __restrict__ Z, const int* __restrict__ aid) {
  extern __shared__ char lds[];
  const int tid = threadIdx.x;
  const int w = tid >> 6;
  const int l = tid & 63;
  const int wr = w >> 1, wc = w & 1;      // wave grid 2Mx2N; per-wave 64x32

  const int bid = blockIdx.x;             // nwg = 512 = 8*64 (XCD swizzle exact)
  const int swz = (bid & 7) * 64 + (bid >> 3);
  const int by = swz >> 3, bx = swz & 7;
  const int brow = by << 7, bcol = bx << 6;

  const int r0 = tid >> 3;                        // 0..31
  const int kc = ((tid & 7) ^ (r0 & 7)) << 3;     // pre-swizzled source col (elems)
  const int wofs = w << 10;                       // per-wave LDS slice (R9 lesson)

  const int lr = l & 15;
  const int lxor = (l & 7) << 4;
  const int kb0 = (l >> 4) << 4;

#define STGL(k_) do {                                                                \
    int kt = (k_); if (kt >= 64) kt -= 64;                                           \
    char* ab = lds + ((kt & 1) << 14) + wofs;                                        \
    char* bb = lds + 32768 + ((kt & 1) << 13) + wofs;                                \
    const ushort_t* spa = A + (size_t)(brow + r0) * KAUG + (kt << 6) + kc;           \
    const ushort_t* spb = B + (size_t)(bcol + r0) * IN_DIM + (kt << 6) + kc;         \
    GLD(spa, ab);                                                                    \
    GLD(spa + (size_t)32 * KAUG, ab + 4096);                                         \
    GLD(spa + (size_t)64 * KAUG, ab + 8192);                                         \
    GLD(spa + (size_t)96 * KAUG, ab + 12288);                                        \
    GLD(spb, bb);                                                                    \
    GLD(spb + (size_t)32 * IN_DIM, bb + 4096);                                       \
  } while (0)

#define LAADDR(c, mb, ks)                                                            \
  (const bf16x8*)(lds + ((c) << 14)                                                  \
                  + (wr * 64 + (mb) * 16 + lr) * 128 + ((((ks) << 6) | kb0) ^ lxor))
#define LBADDR(c, nb, ks)                                                            \
  (const bf16x8*)(lds + 32768 + ((c) << 13)                                          \
                  + (wc * 32 + (nb) * 16 + lr) * 128 + ((((ks) << 6) | kb0) ^ lxor))

  f32x4 acc[4][2] = {};

  STGL(0);
  STGL(1);
  VMC(6);
  __builtin_amdgcn_s_barrier();
  SB();

  for (int k = 0; k < 64; ++k) {
    const int c = k & 1;
    bf16x8 af[4][2], bf[2][2];
#pragma unroll
    for (int mb = 0; mb < 4; ++mb)
#pragma unroll
      for (int ks = 0; ks < 2; ++ks)
        af[mb][ks] = *LAADDR(c, mb, ks);
#pragma unroll
    for (int nb = 0; nb < 2; ++nb)
#pragma unroll
      for (int ks = 0; ks < 2; ++ks)
        bf[nb][ks] = *LBADDR(c, nb, ks);
    LGKM(0); SB();
    __builtin_amdgcn_s_barrier();      // all waves' reads of buf c drained
    STGL(k + 2);                       // overwrite buf c with tile k+2
    __builtin_amdgcn_s_setprio(1);
#pragma unroll
    for (int ks = 0; ks < 2; ++ks)
#pragma unroll
      for (int mb = 0; mb < 4; ++mb)
#pragma unroll
        for (int nb = 0; nb < 2; ++nb)
          acc[mb][nb] = __builtin_amdgcn_mfma_f32_16x16x32_bf16(
              af[mb][ks], bf[nb][ks], acc[mb][nb], 0, 0, 0);
    __builtin_amdgcn_s_setprio(0);
    VMC(6);                            // own slices of tile k+1 landed
    __builtin_amdgcn_s_barrier();      // everyone's slices visible
    SB();
  }

  const int orow = brow + wr * 64 + ((l >> 4) << 2);
#pragma unroll
  for (int mb = 0; mb < 4; ++mb) {
#pragma unroll
    for (int j = 0; j < 4; ++j) {
      int t = orow + mb * 16 + j;
      int ad = aid[t];
#pragma unroll
      for (int nb = 0; nb < 2; ++nb) {
        int cc = bcol + wc * 32 + nb * 16 + lr;
        float v = ((cc >> 6) == ad) ? acc[mb][nb][j] : 0.f;
        Z[(size_t)t * KAUG + IN_DIM + cc] = (ushort_t)f2bf_u(v);
      }
    }
  }
}

// ---------- 256^2-tile sparse-barrier counted-vmcnt GEMM (R5-exact, best: 244 µs) ----------
// C[M,N] = A[M,K](lda) x B[N,K](ldb)^T + bias.  M,N % 256 == 0, K % 128 == 0.
// 8 waves (2Mx4N), per-wave C = 128x64. LDS 128KB: 2 bufs x (A:2x16KB | B:2x16KB).
// 2 barriers + 2 vmcnt(4) per K-tile. B-frags register-pipelined (late LDBH).
// T2 read-swizzle: byte ^= ((row&7)<<4); source pre-swizzled (same involution).
// CLOSED SEARCH LOG (this structure's measured optimum is THIS kernel):
//   R4  32x32x16 frags      -> 2.8e7 bank conflicts, 280 µs (lost)
//   R6  single-barrier/tile -> 250 µs (lost)   R7 quadrant-pipeline -> 256 µs (lost)
//   R11 BK=32 + 64KB LDS 2blk/CU -> 64B/row/tile = half-line waste + L3 thrash,
//       FETCH 340MB->5.8GB, 2967 µs (catastrophic). Staging must be >=128B/row/tile.
__global__ __launch_bounds__(512, 2)
void gemm8(const ushort_t* __restrict__ A, int lda,
           const ushort_t* __restrict__ B, int ldb,
           int M, int N, int K,
           float* __restrict__ out, const float* __restrict__ bias) {
  extern __shared__ char lds[];
  const int tid = threadIdx.x;
  const int l = tid & 63;
  const int w = tid >> 6;       // 0..7
  const int wr = w >> 2;        // 0..1  (A-half / M-half ownership)
  const int wc = w & 3;         // 0..3  (N ownership: B-half wc>>1, 64-col slice wc&1)

  const int nbx = N >> 8;
  const int nwg = nbx * (M >> 8);
  const int cpx = nwg >> 3;     // nwg % 8 == 0 for all our launches
  const int bid = blockIdx.x;
  const int swz = (bid & 7) * cpx + (bid >> 3);
  const int by = swz / nbx, bx = swz - by * nbx;
  const int brow = by << 8, bcol = bx << 8;

  const int r0 = tid >> 3;                        // 0..63
  const int kc = ((tid & 7) ^ (r0 & 7)) << 3;     // element col, same involution as read

  const int lr = l & 15;
  const int lxor = (l & 7) << 4;                  // (row&7)<<4
  const int kb0 = (l >> 4) << 4;                  // 0,16,32,48 bytes

  const int NT = K >> 6;         // K-tiles (even)
  const int NIT = NT >> 1;

#define STG(mat, ld, rowbase, kt_, half, isB) do {                                   \
    int kt = (kt_); if (kt >= NT) kt -= NT;                                          \
    char* lb = lds + (((kt & 1) << 16) | ((isB) << 15) | ((half) << 14) | (w << 10));\
    const ushort_t* sp = (mat) + (size_t)((rowbase) + ((half) << 7) + r0) * (ld)     \
                         + (kt << 6) + kc;                                           \
    GLD(sp, lb);                                                                     \
    GLD(sp + 64 * (ld), lb + 8192);                                                  \
  } while (0)

#define LDA_ADDR(c, q, m, ks)                                                        \
  (const bf16x8*)(lds + (((c) << 16) | (wr << 14))                                   \
                  + ((q) * 32 + (m) * 16 + lr) * 128 + ((((ks) << 6) | kb0) ^ lxor))
#define LDB_ADDR(c, n, ks)                                                           \
  (const bf16x8*)(lds + (((c) << 16) | 32768 | ((wc >> 1) << 14))                    \
                  + (((wc & 1) << 6) + (n) * 16 + lr) * 128 + ((((ks) << 6) | kb0) ^ lxor))

  f32x4 acc[8][4] = {};
  bf16x8 bfr[4][2];   // B-frags for the CURRENT tile; reloaded (next tile) at
                      // the end of each tile's second region (WAR-ordered).

#define LDBH(c, h, dst) do {                                                         \
    _Pragma("unroll") for (int n = 2 * (h); n < 2 * (h) + 2; ++n)                    \
      _Pragma("unroll") for (int ks = 0; ks < 2; ++ks)                               \
        dst[n][ks] = *LDB_ADDR(c, n, ks);                                            \
  } while (0)

#define MFMAQ(q, a_, bfr_)                                                           \
    _Pragma("unroll") for (int ks = 0; ks < 2; ++ks)                                 \
      _Pragma("unroll") for (int m = 0; m < 2; ++m)                                  \
        _Pragma("unroll") for (int n = 0; n < 4; ++n)                                \
          acc[2 * (q) + m][n] = __builtin_amdgcn_mfma_f32_16x16x32_bf16(             \
              a_[m][ks], bfr_[n][ks], acc[2 * (q) + m][n], 0, 0, 0)

  // prologue: T0 A+B complete, T1.B in flight; B(0)->bfr in registers
  STG(A, lda, brow, 0, 0, 0);
  STG(A, lda, brow, 0, 1, 0);
  STG(B, ldb, bcol, 0, 0, 1);
  STG(B, ldb, bcol, 0, 1, 1);
  STG(B, ldb, bcol, 1, 0, 1);
  STG(B, ldb, bcol, 1, 1, 1);
  VMC(4);
  __builtin_amdgcn_s_barrier();
  SB();
  LDBH(0, 0, bfr);
  LDBH(0, 1, bfr);

  // one K-tile: region01 {A-reads q0,q1 | stage A(T+1) | MFMA q0,q1 | vmcnt(4) bar}
  //             region23 {A-reads q2,q3 | stage B(T+2) | MFMA q2,q3 |
  //                       late-load bfr <- B(T+1) | vmcnt(4) bar}
#define TILE(c, TA, TB) do {                                                         \
    {                                                                                \
      bf16x8 a0[2][2], a1[2][2];                                                     \
      _Pragma("unroll") for (int m = 0; m < 2; ++m)                                  \
        _Pragma("unroll") for (int ks = 0; ks < 2; ++ks) {                           \
          a0[m][ks] = *LDA_ADDR(c, 0, m, ks);                                        \
          a1[m][ks] = *LDA_ADDR(c, 1, m, ks);                                        \
        }                                                                            \
      STG(A, lda, brow, TA, 0, 0);                                                   \
      STG(A, lda, brow, TA, 1, 0);                                                   \
      __builtin_amdgcn_s_setprio(1);                                                 \
      MFMAQ(0, a0, bfr);                                                             \
      MFMAQ(1, a1, bfr);                                                             \
      __builtin_amdgcn_s_setprio(0);                                                 \
      VMC(4);                                                                        \
      __builtin_amdgcn_s_barrier();                                                  \
      SB();                                                                          \
    }                                                                                \
    {                                                                                \
      bf16x8 a0[2][2], a1[2][2];                                                     \
      _Pragma("unroll") for (int m = 0; m < 2; ++m)                                  \
        _Pragma("unroll") for (int ks = 0; ks < 2; ++ks) {                           \
          a0[m][ks] = *LDA_ADDR(c, 2, m, ks);                                        \
          a1[m][ks] = *LDA_ADDR(c, 3, m, ks);                                        \
        }                                                                            \
      STG(B, ldb, bcol, TB, 0, 1);                                                   \
      STG(B, ldb, bcol, TB, 1, 1);                                                   \
      __builtin_amdgcn_s_setprio(1);                                                 \
      MFMAQ(2, a0, bfr);                                                             \
      MFMAQ(3, a1, bfr);                                                             \
      __builtin_amdgcn_s_setprio(0);                                                 \
      LDBH((c) ^ 1, 0, bfr);                                                         \
      LDBH((c) ^ 1, 1, bfr);                                                         \
      VMC(4);                                                                        \
      __builtin_amdgcn_s_barrier();                                                  \
      SB();                                                                          \
    }                                                                                \
  } while (0)

  for (int it = 0; it < NIT; ++it) {
    const int T = it << 1;
    TILE(0, T + 1, T + 2);
    TILE(1, T + 2, T + 3);
  }

  // epilogue: D frag layout row=(l>>4)*4+j, col=l&15 (verified R1-R10)
  const int orow = brow + (wr << 7) + ((l >> 4) << 2);
  const int ocol = bcol + (wc << 6) + lr;
  float bb[4];
#pragma unroll
  for (int n = 0; n < 4; ++n) bb[n] = bias[ocol + n * 16];
#pragma unroll
  for (int mi = 0; mi < 8; ++mi)
#pragma unroll
    for (int n = 0; n < 4; ++n)
#pragma unroll
      for (int j = 0; j < 4; ++j)
        out[(size_t)(orow + mi * 16 + j) * N + ocol + n * 16] = acc[mi][n][j] + bb[n];
}

extern "C" void kernel_launch(void* const* d_in, const int* in_sizes, int n_in,
                              void* d_out, int out_size, void* d_ws, size_t ws_size,
                              hipStream_t stream) {
  const float* x    = (const float*)d_in[0];
  const float* wgt  = (const float*)d_in[1];
  const float* bias = (const float*)d_in[2];
  const float* Abuf = (const float*)d_in[3];
  const float* Bbuf = (const float*)d_in[4];
  const int*   aid  = (const int*)d_in[5];
  float* out = (float*)d_out;

  // workspace: Xaug[8192][4608] | Waug[4096][4608] | Abf[512][4096]  (bf16 as ushort)
  ushort_t* Xaug = (ushort_t*)d_ws;
  ushort_t* Waug = Xaug + (size_t)NUM_TOKENS * KAUG;
  ushort_t* Abf  = Waug + (size_t)OUT_DIM * KAUG;

  // all conversions in one streaming launch
  k_cvt_all<<<(XT8 + WT8 + AT8 + BT8) / 256, 256, 0, stream>>>(
      x, wgt, Abuf, Bbuf, Xaug, Waug, Abf);

  // Z = mask(X @ A_flat^T) into Xaug cols 4096..4607: M=8192 N=512 K=4096
  gemm_lora_a<<<512, 256, 49152, stream>>>(Xaug, Abf, Xaug, aid);

  // out = Xaug @ Waug^T + bias: M=8192 N=4096 K=4608 (72 K-tiles, 36 iters)
  gemm8<<<(NUM_TOKENS / 256) * (OUT_DIM / 256), 512, 131072, stream>>>(
      Xaug, KAUG, Waug, KAUG, NUM_TOKENS, OUT_DIM, KAUG, out, bias);
}